// Round 13
// baseline (3205.043 us; speedup 1.0000x reference)
//
#include <hip/hip_runtime.h>
#include <hip/hip_bf16.h>
#include <cstdint>
#include <cstddef>

#define BB 64
#define TT 512
#define II 1024
#define HH 1024
#define CSLOT 128   // ring slots/group (32MB total >= L2 aggregate: fresh-miss holds)

typedef __attribute__((ext_vector_type(8))) short bf16x8;
typedef __attribute__((ext_vector_type(4))) float f32x4;
typedef __attribute__((ext_vector_type(8))) ushort ushort8v;
typedef __attribute__((ext_vector_type(4))) unsigned int u32x4;

// ---- ws layout (bytes) ----
#define OFF_WHH   0ull            // bf16 [4096][1024]
#define OFF_WIH   8388608ull      // bf16 [4096][1024]
#define OFF_BIAS  16777216ull     // f32 [4096]
#define OFF_FL    16793600ull     // u32 [4][512][64] per-producer flags (512 KB)
#define OFF_HROT  17317888ull     // u32 [4][128][16][1024] tagged exchange (32MB)
#define OFF_HBUF  50872320ull     // bf16 [2][64][1024] (fallback)
#define OFF_CBUF  51134464ull     // f32 [64][1024]     (fallback)
#define OFF_PRE   51396608ull     // bf16 [512][64][4096]
#define OFF_XB_B  51396608ull     // bf16 [T][B][I] (fallback tier B)
#define NEED_A    319832064ull
#define NEED_B    118505472ull

__device__ __forceinline__ ushort f2b(float f) {
  union { float f; uint32_t u; } v; v.f = f;
  uint32_t r = v.u + 0x7fffu + ((v.u >> 16) & 1u);
  return (ushort)(r >> 16);
}
__device__ __forceinline__ float b2f(ushort u) {
  union { uint32_t u; float f; } v; v.u = ((uint32_t)u) << 16; return v.f;
}
__device__ __forceinline__ float sigm(float x) { return 1.0f / (1.0f + __expf(-x)); }
__device__ __forceinline__ float tanh_f(float x) {
  float e = __expf(2.0f * x);
  return 1.0f - 2.0f / (e + 1.0f);
}

// ---------- prep ----------
__global__ void k_prep(const float* __restrict__ wih, const float* __restrict__ whh,
                       const float* __restrict__ bih, const float* __restrict__ bhh,
                       const float* __restrict__ hx, const float* __restrict__ cx,
                       ushort* __restrict__ Whh_b, ushort* __restrict__ Wih_b,
                       float* __restrict__ bias, ushort* __restrict__ hbuf0,
                       float* __restrict__ cbuf, uint32_t* __restrict__ hrot,
                       uint32_t* __restrict__ fl) {
  const int tid = blockIdx.x * blockDim.x + threadIdx.x;
  const int nth = gridDim.x * blockDim.x;
  for (int idx = tid; idx < 4096 * 128; idx += nth) {   // chunks of 8
    const size_t o = (size_t)idx * 8;
    f32x4 h0 = *(const f32x4*)(whh + o), h1 = *(const f32x4*)(whh + o + 4);
    f32x4 i0 = *(const f32x4*)(wih + o), i1 = *(const f32x4*)(wih + o + 4);
    ushort8v a, b;
    a[0]=f2b(h0[0]); a[1]=f2b(h0[1]); a[2]=f2b(h0[2]); a[3]=f2b(h0[3]);
    a[4]=f2b(h1[0]); a[5]=f2b(h1[1]); a[6]=f2b(h1[2]); a[7]=f2b(h1[3]);
    b[0]=f2b(i0[0]); b[1]=f2b(i0[1]); b[2]=f2b(i0[2]); b[3]=f2b(i0[3]);
    b[4]=f2b(i1[0]); b[5]=f2b(i1[1]); b[6]=f2b(i1[2]); b[7]=f2b(i1[3]);
    *(ushort8v*)(Whh_b + o) = a;
    *(ushort8v*)(Wih_b + o) = b;
  }
  for (int idx = tid; idx < 4096; idx += nth) bias[idx] = bih[idx] + bhh[idx];
  // clear ALL ring tags except slot 0 (replay safety)
  for (int idx = tid; idx < 4 * CSLOT * 16384; idx += nth) {
    const int slot = (idx >> 14) & (CSLOT - 1);
    if (slot != 0) hrot[idx] = 0xFFFF0000u;
  }
  // clear per-producer flags (one-shot per t; 0xFFFFFFFF != any t)
  for (int idx = tid; idx < 4 * 512 * 64; idx += nth) fl[idx] = 0xFFFFFFFFu;
  for (int idx = tid; idx < BB * HH; idx += nth) {
    const ushort hb = f2b(hx[idx]);
    hbuf0[idx] = hb;
    cbuf[idx] = cx[idx];
    const int brow = idx >> 10, hh = idx & 1023;
    const int g = brow >> 4, r = brow & 15;
    hrot[(size_t)g * CSLOT * 16384 + (size_t)r * 1024 + hh] = (uint32_t)hb;  // tag 0
  }
}

// ---------- x f32 [B][T][I] -> bf16 [T][B][I] (fallback tier) ----------
__global__ void k_convx_tb(const float* __restrict__ x, ushort* __restrict__ xb) {
  const int tid = blockIdx.x * blockDim.x + threadIdx.x;
  const int nth = gridDim.x * blockDim.x;
  for (int idx = tid; idx < TT * BB * (II / 8); idx += nth) {
    const int i8 = idx & 127;
    const int tb = idx >> 7;
    const int t = tb >> 6, b = tb & 63;
    const float* src = x + ((size_t)b * TT + t) * II + (size_t)i8 * 8;
    f32x4 v0 = *(const f32x4*)src, v1 = *(const f32x4*)(src + 4);
    ushort8v o;
    o[0]=f2b(v0[0]); o[1]=f2b(v0[1]); o[2]=f2b(v0[2]); o[3]=f2b(v0[3]);
    o[4]=f2b(v1[0]); o[5]=f2b(v1[1]); o[6]=f2b(v1[2]); o[7]=f2b(v1[3]);
    *(ushort8v*)(xb + (size_t)idx * 8) = o;
  }
}

// ---------- pre_x GEMM ([32768,1024] x [4096,1024]^T), inline f32->bf16 A ----------
template<bool FASTA>
__global__ void __launch_bounds__(256)
k_gemm(const ushort* __restrict__ xb, const float* __restrict__ xf,
       const ushort* __restrict__ Wih, ushort* __restrict__ pre) {
  __shared__ ushort As[2][8192];
  __shared__ ushort Bs[2][8192];
  const int tid = threadIdx.x;
  const int lane = tid & 63;
  const int w = tid >> 6;
  const int wm = w & 1, wn = w >> 1;
  const int l15 = lane & 15, kg = lane >> 4;
  const int work = (blockIdx.x & 7) * 1024 + (blockIdx.x >> 3);
  const int rp = work >> 5, cp = work & 31;
  const int m0 = rp * 128, n0 = cp * 128;

  f32x4 acc[4][4];
#pragma unroll
  for (int i = 0; i < 4; ++i)
#pragma unroll
    for (int j = 0; j < 4; ++j) acc[i][j] = f32x4{0.f, 0.f, 0.f, 0.f};

  bf16x8 ra[4], rb[4];

#define LOADTILE(KT)                                                          \
  {                                                                           \
    _Pragma("unroll")                                                         \
    for (int it = 0; it < 4; ++it) {                                          \
      const int idx = it * 256 + tid;                                         \
      const int row = idx >> 3, seg = idx & 7;                                \
      if (FASTA) {                                                            \
        ra[it] = *(const bf16x8*)(xb + (size_t)(m0 + row) * 1024 + (KT) * 64 + seg * 8); \
      } else {                                                                \
        const float* s = xf + (size_t)(m0 + row) * 1024 + (KT) * 64 + seg * 8;\
        f32x4 v0 = *(const f32x4*)s, v1 = *(const f32x4*)(s + 4);             \
        bf16x8 o;                                                             \
        o[0]=(short)f2b(v0[0]); o[1]=(short)f2b(v0[1]);                       \
        o[2]=(short)f2b(v0[2]); o[3]=(short)f2b(v0[3]);                       \
        o[4]=(short)f2b(v1[0]); o[5]=(short)f2b(v1[1]);                       \
        o[6]=(short)f2b(v1[2]); o[7]=(short)f2b(v1[3]);                       \
        ra[it] = o;                                                           \
      }                                                                       \
      rb[it] = *(const bf16x8*)(Wih + (size_t)(n0 + row) * 1024 + (KT) * 64 + seg * 8); \
    }                                                                         \
  }

#define WRITETILE(BUF)                                                        \
  {                                                                           \
    _Pragma("unroll")                                                         \
    for (int it = 0; it < 4; ++it) {                                          \
      const int idx = it * 256 + tid;                                         \
      const int row = idx >> 3, seg = idx & 7;                                \
      const int off = row * 64 + ((seg ^ (row & 7)) << 3);                    \
      *(bf16x8*)(&As[BUF][off]) = ra[it];                                     \
      *(bf16x8*)(&Bs[BUF][off]) = rb[it];                                     \
    }                                                                         \
  }

  LOADTILE(0);
  WRITETILE(0);
  __syncthreads();

#pragma unroll 1
  for (int kt = 0; kt < 16; ++kt) {
    const int cur = kt & 1;
    if (kt < 15) LOADTILE(kt + 1);
#pragma unroll
    for (int ks = 0; ks < 2; ++ks) {
      bf16x8 af[4], bf_[4];
      const int koff = ks * 32 + kg * 8;
      const int swz = koff ^ ((l15 & 7) << 3);
#pragma unroll
      for (int i = 0; i < 4; ++i) {
        const int arow = wm * 64 + i * 16 + l15;
        af[i] = *(const bf16x8*)(&As[cur][arow * 64 + swz]);
        const int brow = wn * 64 + i * 16 + l15;
        bf_[i] = *(const bf16x8*)(&Bs[cur][brow * 64 + swz]);
      }
#pragma unroll
      for (int i = 0; i < 4; ++i)
#pragma unroll
        for (int j = 0; j < 4; ++j)
          acc[i][j] = __builtin_amdgcn_mfma_f32_16x16x32_bf16(af[i], bf_[j], acc[i][j], 0, 0, 0);
    }
    if (kt < 15) WRITETILE(cur ^ 1);
    __syncthreads();
  }

#pragma unroll
  for (int i = 0; i < 4; ++i)
#pragma unroll
    for (int j = 0; j < 4; ++j)
#pragma unroll
      for (int e = 0; e < 4; ++e) {
        const int m = m0 + wm * 64 + i * 16 + kg * 4 + e;
        const int n = n0 + wn * 64 + j * 16 + l15;
        pre[((size_t)(m & 511) * 64 + (m >> 9)) * 4096 + n] = f2b(acc[i][j][e]);
      }
#undef LOADTILE
#undef WRITETILE
}

// ---------- persistent recurrence: drained flags + per-wave polling ----------
// r12 protocol, refined: (1) flag stored AFTER the loop-end __syncthreads
// (which drains vmcnt(0) for ALL waves -> every payload store is acked before
// the flag exists: consumer fast path deterministic); (2) each wave polls only
// its 16 source producers (one 64B line, single sc1 vector load; tail =
// max-of-16, polls overlap other waves' loads); (3) poll -> load -> MFMA ->
// red-write -> barrier -> reduce/gates -> stores -> barrier(+drain) -> flag.
// Tags + selective sc1 retry stay as the correctness backstop (any mapping).
__global__ void __launch_bounds__(256, 1)
k_recur(const ushort* __restrict__ Whh_b, const float* __restrict__ bias,
        uint32_t* __restrict__ hrot, const ushort* __restrict__ pre,
        const float* __restrict__ cx,
        const float* __restrict__ wci, const float* __restrict__ wcf,
        const float* __restrict__ wco, float* __restrict__ out,
        uint32_t* __restrict__ fl) {
  __shared__ float red[4][4][16][17];
  const int tid = threadIdx.x;
  const int lane = tid & 63;
  const int w = tid >> 6;
  const int l15 = lane & 15, kg = lane >> 4;
  const int g = blockIdx.x & 3, j = blockIdx.x >> 2;

  // W frags (B-operand): col = gate*1024 + j*16 + l15, k = w*256 + ks*32 + kg*8
  bf16x8 wf[4][8];
#pragma unroll
  for (int gate = 0; gate < 4; ++gate)
#pragma unroll
    for (int ks = 0; ks < 8; ++ks)
      wf[gate][ks] = *(const bf16x8*)(Whh_b
          + (size_t)(gate * 1024 + j * 16 + l15) * 1024 + (w * 8 + ks) * 32 + kg * 8);

  const int grow = tid >> 4, ghl = tid & 15;
  const int brow = g * 16 + grow;
  const int hidx = j * 16 + ghl;
  const float bi = bias[hidx], bff = bias[1024 + hidx],
              bg = bias[2048 + hidx], bo = bias[3072 + hidx];
  const float pci = wci[hidx], pcf = wcf[hidx], pco = wco[hidx];
  float creg = cx[brow * 1024 + hidx];

  const size_t gbase = (size_t)g * CSLOT * 16384;
  const uint32_t* flg = fl + (size_t)g * 512 * 64;     // this group's flag rows
  const int rowoff = l15 * 1024 + w * 256 + kg * 8;    // lane's row + k-slice
  const int srcj = w * 16 + l15;   // wave w's source producers (16, 4x dup/lane)

  // preload pre[0]
  const ushort* pp0 = pre + ((size_t)brow) * 4096 + hidx;
  float pxi = b2f(pp0[0]), pxf = b2f(pp0[1024]),
        pxg = b2f(pp0[2048]), pxo = b2f(pp0[3072]);

#pragma unroll 1
  for (int t = 0; t < 512; ++t) {
    // [A] per-wave flag poll: only THIS wave's 16 source producers (1 line)
    if (t > 0) {
      const uint32_t* fp_ = flg + (size_t)t * 64 + srcj;
      uint32_t v = __hip_atomic_load(fp_, __ATOMIC_RELAXED, __HIP_MEMORY_SCOPE_AGENT);
      while (!__all(v == (uint32_t)t)) {
        __builtin_amdgcn_s_sleep(1);
        v = __hip_atomic_load(fp_, __ATOMIC_RELAXED, __HIP_MEMORY_SCOPE_AGENT);
      }
    }

    // [B] payload loads (plain: fresh MALL fill, L2-shared) + tag backstop
    const uint32_t* hp = hrot + gbase + (size_t)(t & (CSLOT - 1)) * 16384 + rowoff;
    const uint32_t tg = (uint32_t)t << 16;
    uint32_t q[64];
#pragma unroll
    for (int ks = 0; ks < 8; ++ks) {
      u32x4 a = *(const u32x4*)(hp + ks * 32);
      u32x4 b = *(const u32x4*)(hp + ks * 32 + 4);
      q[ks*8+0]=a[0]; q[ks*8+1]=a[1]; q[ks*8+2]=a[2]; q[ks*8+3]=a[3];
      q[ks*8+4]=b[0]; q[ks*8+5]=b[1]; q[ks*8+6]=b[2]; q[ks*8+7]=b[3];
    }
    uint32_t bad = 0;
#pragma unroll
    for (int i = 0; i < 64; ++i) bad |= (q[i] ^ tg);
    while (bad >> 16) {
      // selective sc1 retry of ONLY straggler words (rare: flag is post-drain)
#pragma unroll
      for (int i = 0; i < 64; ++i)
        if ((q[i] ^ tg) >> 16)
          q[i] = __hip_atomic_load(hp + (i >> 3) * 32 + (i & 7),
                                   __ATOMIC_RELAXED, __HIP_MEMORY_SCOPE_AGENT);
      bad = 0;
#pragma unroll
      for (int i = 0; i < 64; ++i) bad |= (q[i] ^ tg);
      if (bad >> 16) __builtin_amdgcn_s_sleep(1);
    }
    bf16x8 af[8];
#pragma unroll
    for (int ks = 0; ks < 8; ++ks) {
      bf16x8 a;
      a[0]=(short)(q[ks*8+0]&0xFFFF); a[1]=(short)(q[ks*8+1]&0xFFFF);
      a[2]=(short)(q[ks*8+2]&0xFFFF); a[3]=(short)(q[ks*8+3]&0xFFFF);
      a[4]=(short)(q[ks*8+4]&0xFFFF); a[5]=(short)(q[ks*8+5]&0xFFFF);
      a[6]=(short)(q[ks*8+6]&0xFFFF); a[7]=(short)(q[ks*8+7]&0xFFFF);
      af[ks] = a;
    }

    // prefetch pre[t+1] (register-held; independent of exchange)
    const int tn = (t < 511) ? (t + 1) : 511;
    const ushort* pp = pre + ((size_t)tn * 64 + brow) * 4096 + hidx;
    const ushort nn0 = pp[0], nn1 = pp[1024], nn2 = pp[2048], nn3 = pp[3072];

    // [D] MFMA (prev step's loop-end barrier protects red[] reuse)
    f32x4 acc[4];
#pragma unroll
    for (int gate = 0; gate < 4; ++gate) acc[gate] = f32x4{0.f, 0.f, 0.f, 0.f};
#pragma unroll
    for (int ks = 0; ks < 8; ++ks)
#pragma unroll
      for (int gate = 0; gate < 4; ++gate)
        acc[gate] = __builtin_amdgcn_mfma_f32_16x16x32_bf16(af[ks], wf[gate][ks], acc[gate], 0, 0, 0);

    // K-partials -> LDS (C/D: col=l15, row=kg*4+e)
#pragma unroll
    for (int gate = 0; gate < 4; ++gate)
#pragma unroll
      for (int e = 0; e < 4; ++e)
        red[w][gate][kg * 4 + e][l15] = acc[gate][e];
    __syncthreads();   // [E]

    // [F] reduce + gates
    float s0 = 0.f, s1 = 0.f, s2 = 0.f, s3 = 0.f;
#pragma unroll
    for (int ww = 0; ww < 4; ++ww) {
      s0 += red[ww][0][grow][ghl];
      s1 += red[ww][1][grow][ghl];
      s2 += red[ww][2][grow][ghl];
      s3 += red[ww][3][grow][ghl];
    }
    const float ig = sigm(s0 + bi + pxi + pci * creg);
    const float fg = sigm(s1 + bff + pxf + pcf * creg);
    const float gg = tanh_f(s2 + bg + pxg);
    const float cy = fg * creg + ig * gg;
    const float og = sigm(s3 + bo + pxo + pco * cy);
    const float hy = og * tanh_f(cy);
    creg = cy;
    // [G] stores: exchange payload first, then out
    if (t < 511) {
      const uint32_t word = (((uint32_t)(t + 1)) << 16) | (uint32_t)f2b(hy);
      __hip_atomic_store(&hrot[gbase + (size_t)((t + 1) & (CSLOT - 1)) * 16384
                               + (size_t)grow * 1024 + hidx],
                         word, __ATOMIC_RELAXED, __HIP_MEMORY_SCOPE_AGENT);
    }
    __builtin_nontemporal_store(hy,
        &out[(size_t)brow * 524288 + (size_t)t * 1024 + hidx]);
    pxi = b2f(nn0); pxf = b2f(nn1); pxg = b2f(nn2); pxo = b2f(nn3);

    __syncthreads();   // [H] drains vmcnt(0) for ALL waves: payload acked
    // [I] flag AFTER the drain: consumers never see flag before payload
    if (t < 511 && tid == 0)
      __hip_atomic_store((uint32_t*)(flg + (size_t)(t + 1) * 64 + j),
                         (uint32_t)(t + 1), __ATOMIC_RELAXED,
                         __HIP_MEMORY_SCOPE_AGENT);
  }
}

// ---------- fallback: per-timestep kernel (known-pass) ----------
template<bool XB>
__global__ void __launch_bounds__(256)
k_step2(const ushort* __restrict__ Whh, const ushort* __restrict__ Wih,
        const float* __restrict__ bias,
        const ushort* __restrict__ hprev, ushort* __restrict__ hnext,
        float* __restrict__ cbuf, const ushort* __restrict__ xb,
        const float* __restrict__ x,
        const float* __restrict__ wci, const float* __restrict__ wcf,
        const float* __restrict__ wco, float* __restrict__ out, int t) {
  __shared__ float pre[32][33];
  const int lane = threadIdx.x & 63;
  const int w = threadIdx.x >> 6;
  const int mt = w & 1, ct = w >> 1;
  const int mg = blockIdx.x & 1, cg = blockIdx.x >> 1;
  const int l15 = lane & 15, kg = lane >> 4;
  const int arow = mg * 32 + mt * 16 + l15;
  const int gate = ct * 2 + (l15 >> 3);
  const int hl = l15 & 7;
  const int gcol = gate * HH + cg * 8 + hl;

  const ushort* wr = Whh + (size_t)gcol * 1024 + kg * 8;
  const ushort* hr = hprev + (size_t)arow * HH + kg * 8;

  f32x4 acc0 = {0.f,0.f,0.f,0.f};
  f32x4 acc1 = {0.f,0.f,0.f,0.f};

#pragma unroll 8
  for (int ks = 0; ks < 32; ks += 2) {
    bf16x8 a0 = *(const bf16x8*)(hr + ks * 32);
    bf16x8 b0 = *(const bf16x8*)(wr + ks * 32);
    acc0 = __builtin_amdgcn_mfma_f32_16x16x32_bf16(a0, b0, acc0, 0, 0, 0);
    bf16x8 a1 = *(const bf16x8*)(hr + ks * 32 + 32);
    bf16x8 b1 = *(const bf16x8*)(wr + ks * 32 + 32);
    acc1 = __builtin_amdgcn_mfma_f32_16x16x32_bf16(a1, b1, acc1, 0, 0, 0);
  }
  const ushort* wrx = Wih + (size_t)gcol * 1024 + kg * 8;
  if (XB) {
    const ushort* xr = xb + ((size_t)t * BB + arow) * II + kg * 8;
#pragma unroll 8
    for (int ks = 0; ks < 32; ks += 2) {
      bf16x8 a0 = *(const bf16x8*)(xr + ks * 32);
      bf16x8 b0 = *(const bf16x8*)(wrx + ks * 32);
      acc0 = __builtin_amdgcn_mfma_f32_16x16x32_bf16(a0, b0, acc0, 0, 0, 0);
      bf16x8 a1 = *(const bf16x8*)(xr + ks * 32 + 32);
      bf16x8 b1 = *(const bf16x8*)(wrx + ks * 32 + 32);
      acc1 = __builtin_amdgcn_mfma_f32_16x16x32_bf16(a1, b1, acc1, 0, 0, 0);
    }
  } else {
    const float* xr = x + ((size_t)arow * TT + t) * II + kg * 8;
#pragma unroll 4
    for (int ks = 0; ks < 32; ++ks) {
      f32x4 v0 = *(const f32x4*)(xr + ks * 32);
      f32x4 v1 = *(const f32x4*)(xr + ks * 32 + 4);
      bf16x8 a;
      a[0]=(short)f2b(v0[0]); a[1]=(short)f2b(v0[1]);
      a[2]=(short)f2b(v0[2]); a[3]=(short)f2b(v0[3]);
      a[4]=(short)f2b(v1[0]); a[5]=(short)f2b(v1[1]);
      a[6]=(short)f2b(v1[2]); a[7]=(short)f2b(v1[3]);
      bf16x8 b0 = *(const bf16x8*)(wrx + ks * 32);
      acc0 = __builtin_amdgcn_mfma_f32_16x16x32_bf16(a, b0, acc0, 0, 0, 0);
    }
  }
  f32x4 acc = acc0 + acc1;

  const float bv = bias[gcol];
  const int lr0 = mt * 16 + kg * 4;
  const int lc2 = ct * 16 + l15;
#pragma unroll
  for (int jj = 0; jj < 4; ++jj) pre[lr0 + jj][lc2] = acc[jj] + bv;
  __syncthreads();

  const int tid = threadIdx.x;
  const int lr = tid >> 3;
  const int hl2 = tid & 7;
  const int b = mg * 32 + lr;
  const int hi = cg * 8 + hl2;
  const float ip = pre[lr][hl2];
  const float fp = pre[lr][8 + hl2];
  const float gp = pre[lr][16 + hl2];
  const float op = pre[lr][24 + hl2];
  const float c = cbuf[b * HH + hi];
  const float ig = sigm(ip + wci[hi] * c);
  const float fg = sigm(fp + wcf[hi] * c);
  const float gg = tanh_f(gp);
  const float cy = fg * c + ig * gg;
  const float og = sigm(op + wco[hi] * cy);
  const float hy = og * tanh_f(cy);
  cbuf[b * HH + hi] = cy;
  hnext[b * HH + hi] = f2b(hy);
  out[((size_t)b * TT + t) * HH + hi] = hy;
}

extern "C" void kernel_launch(void* const* d_in, const int* in_sizes, int n_in,
                              void* d_out, int out_size, void* d_ws, size_t ws_size,
                              hipStream_t stream) {
  const float* x   = (const float*)d_in[0];
  const float* hx  = (const float*)d_in[1];
  const float* cx  = (const float*)d_in[2];
  const float* wih = (const float*)d_in[3];
  const float* whh = (const float*)d_in[4];
  const float* bih = (const float*)d_in[5];
  const float* bhh = (const float*)d_in[6];
  const float* wci = (const float*)d_in[7];
  const float* wcf = (const float*)d_in[8];
  const float* wco = (const float*)d_in[9];
  float* out = (float*)d_out;

  char* ws = (char*)d_ws;
  ushort*   Whh_b = (ushort*)(ws + OFF_WHH);
  ushort*   Wih_b = (ushort*)(ws + OFF_WIH);
  float*    bias  = (float*)(ws + OFF_BIAS);
  uint32_t* fl    = (uint32_t*)(ws + OFF_FL);
  uint32_t* hrot  = (uint32_t*)(ws + OFF_HROT);
  ushort*   hbuf  = (ushort*)(ws + OFF_HBUF);
  float*    cbuf  = (float*)(ws + OFF_CBUF);
  ushort*   pre   = (ushort*)(ws + OFF_PRE);

  k_prep<<<512, 256, 0, stream>>>(wih, whh, bih, bhh, hx, cx,
                                  Whh_b, Wih_b, bias, hbuf, cbuf, hrot, fl);

  if (ws_size >= NEED_A) {
    k_gemm<false><<<8192, 256, 0, stream>>>(nullptr, x, Wih_b, pre);
    k_recur<<<256, 256, 0, stream>>>(Whh_b, bias, hrot, pre, cx,
                                     wci, wcf, wco, out, fl);
  } else if (ws_size >= NEED_B) {
    ushort* xb = (ushort*)(ws + OFF_XB_B);
    k_convx_tb<<<1024, 256, 0, stream>>>(x, xb);
    for (int t = 0; t < TT; ++t) {
      const ushort* hp = hbuf + (size_t)(t & 1) * BB * HH;
      ushort* hn = hbuf + (size_t)((t + 1) & 1) * BB * HH;
      k_step2<true><<<256, 256, 0, stream>>>(Whh_b, Wih_b, bias, hp, hn, cbuf,
                                             xb, x, wci, wcf, wco, out, t);
    }
  } else {
    for (int t = 0; t < TT; ++t) {
      const ushort* hp = hbuf + (size_t)(t & 1) * BB * HH;
      ushort* hn = hbuf + (size_t)((t + 1) & 1) * BB * HH;
      k_step2<false><<<256, 256, 0, stream>>>(Whh_b, Wih_b, bias, hp, hn, cbuf,
                                              nullptr, x, wci, wcf, wco, out, t);
    }
  }

  // state outputs = INITIAL (hx, cx), per reference
  hipMemcpyAsync(out + 33554432, hx, (size_t)BB * HH * 4,
                 hipMemcpyDeviceToDevice, stream);
  hipMemcpyAsync(out + 33554432 + 65536, cx, (size_t)BB * HH * 4,
                 hipMemcpyDeviceToDevice, stream);
}

// Round 14
// 2981.697 us; speedup vs baseline: 1.0749x; 1.0749x over previous
//
#include <hip/hip_runtime.h>
#include <hip/hip_bf16.h>
#include <cstdint>
#include <cstddef>

#define BB 64
#define TT 512
#define II 1024
#define HH 1024
#define CSLOT 128   // ring slots/group (32MB total >= L2 aggregate: fresh-miss holds)

typedef __attribute__((ext_vector_type(8))) short bf16x8;
typedef __attribute__((ext_vector_type(4))) float f32x4;
typedef __attribute__((ext_vector_type(8))) ushort ushort8v;
typedef __attribute__((ext_vector_type(4))) unsigned int u32x4;

// ---- ws layout (bytes) ----
#define OFF_WHH   0ull            // bf16 [4096][1024]
#define OFF_WIH   8388608ull      // bf16 [4096][1024]
#define OFF_BIAS  16777216ull     // f32 [4096]
#define OFF_FL    16793600ull     // u32 [4][512][64] per-producer flags (512 KB)
#define OFF_HROT  17317888ull     // u32 [4][128][16][1024] tagged exchange (32MB)
#define OFF_HBUF  50872320ull     // bf16 [2][64][1024] (fallback)
#define OFF_CBUF  51134464ull     // f32 [64][1024]     (fallback)
#define OFF_PRE   51396608ull     // bf16 [512][64][4096]
#define OFF_XB_A  319832064ull    // bf16 [32768][1024] (tier A2 only)
#define OFF_XB_B  51396608ull     // bf16 [T][B][I] (fallback tier B)
#define NEED_A2   386940928ull
#define NEED_A    319832064ull
#define NEED_B    118505472ull

__device__ __forceinline__ ushort f2b(float f) {
  union { float f; uint32_t u; } v; v.f = f;
  uint32_t r = v.u + 0x7fffu + ((v.u >> 16) & 1u);
  return (ushort)(r >> 16);
}
__device__ __forceinline__ float b2f(ushort u) {
  union { uint32_t u; float f; } v; v.u = ((uint32_t)u) << 16; return v.f;
}
__device__ __forceinline__ float sigm(float x) { return 1.0f / (1.0f + __expf(-x)); }
__device__ __forceinline__ float tanh_f(float x) {
  float e = __expf(2.0f * x);
  return 1.0f - 2.0f / (e + 1.0f);
}

// ---------- prep ----------
__global__ void k_prep(const float* __restrict__ wih, const float* __restrict__ whh,
                       const float* __restrict__ bih, const float* __restrict__ bhh,
                       const float* __restrict__ hx, const float* __restrict__ cx,
                       ushort* __restrict__ Whh_b, ushort* __restrict__ Wih_b,
                       float* __restrict__ bias, ushort* __restrict__ hbuf0,
                       float* __restrict__ cbuf, uint32_t* __restrict__ hrot,
                       uint32_t* __restrict__ fl) {
  const int tid = blockIdx.x * blockDim.x + threadIdx.x;
  const int nth = gridDim.x * blockDim.x;
  for (int idx = tid; idx < 4096 * 128; idx += nth) {   // chunks of 8
    const size_t o = (size_t)idx * 8;
    f32x4 h0 = *(const f32x4*)(whh + o), h1 = *(const f32x4*)(whh + o + 4);
    f32x4 i0 = *(const f32x4*)(wih + o), i1 = *(const f32x4*)(wih + o + 4);
    ushort8v a, b;
    a[0]=f2b(h0[0]); a[1]=f2b(h0[1]); a[2]=f2b(h0[2]); a[3]=f2b(h0[3]);
    a[4]=f2b(h1[0]); a[5]=f2b(h1[1]); a[6]=f2b(h1[2]); a[7]=f2b(h1[3]);
    b[0]=f2b(i0[0]); b[1]=f2b(i0[1]); b[2]=f2b(i0[2]); b[3]=f2b(i0[3]);
    b[4]=f2b(i1[0]); b[5]=f2b(i1[1]); b[6]=f2b(i1[2]); b[7]=f2b(i1[3]);
    *(ushort8v*)(Whh_b + o) = a;
    *(ushort8v*)(Wih_b + o) = b;
  }
  for (int idx = tid; idx < 4096; idx += nth) bias[idx] = bih[idx] + bhh[idx];
  // clear ALL ring tags except slot 0 (replay safety)
  for (int idx = tid; idx < 4 * CSLOT * 16384; idx += nth) {
    const int slot = (idx >> 14) & (CSLOT - 1);
    if (slot != 0) hrot[idx] = 0xFFFF0000u;
  }
  // clear per-producer flags (one-shot per t; 0xFFFFFFFF != any t)
  for (int idx = tid; idx < 4 * 512 * 64; idx += nth) fl[idx] = 0xFFFFFFFFu;
  for (int idx = tid; idx < BB * HH; idx += nth) {
    const ushort hb = f2b(hx[idx]);
    hbuf0[idx] = hb;
    cbuf[idx] = cx[idx];
    const int brow = idx >> 10, hh = idx & 1023;
    const int g = brow >> 4, r = brow & 15;
    hrot[(size_t)g * CSLOT * 16384 + (size_t)r * 1024 + hh] = (uint32_t)hb;  // tag 0
  }
}

// ---------- x f32 -> bf16, flat [(b*512+t)][I] (tier A2) ----------
__global__ void k_convx_flat(const float* __restrict__ x, ushort* __restrict__ xb) {
  const int tid = blockIdx.x * blockDim.x + threadIdx.x;
  const int nth = gridDim.x * blockDim.x;
  for (size_t idx = tid; idx < 4194304ull; idx += nth) {
    const float* s = x + idx * 8;
    f32x4 v0 = *(const f32x4*)s, v1 = *(const f32x4*)(s + 4);
    ushort8v o;
    o[0]=f2b(v0[0]); o[1]=f2b(v0[1]); o[2]=f2b(v0[2]); o[3]=f2b(v0[3]);
    o[4]=f2b(v1[0]); o[5]=f2b(v1[1]); o[6]=f2b(v1[2]); o[7]=f2b(v1[3]);
    *(ushort8v*)(xb + idx * 8) = o;
  }
}

// ---------- x f32 [B][T][I] -> bf16 [T][B][I] (fallback tier B) ----------
__global__ void k_convx_tb(const float* __restrict__ x, ushort* __restrict__ xb) {
  const int tid = blockIdx.x * blockDim.x + threadIdx.x;
  const int nth = gridDim.x * blockDim.x;
  for (int idx = tid; idx < TT * BB * (II / 8); idx += nth) {
    const int i8 = idx & 127;
    const int tb = idx >> 7;
    const int t = tb >> 6, b = tb & 63;
    const float* src = x + ((size_t)b * TT + t) * II + (size_t)i8 * 8;
    f32x4 v0 = *(const f32x4*)src, v1 = *(const f32x4*)(src + 4);
    ushort8v o;
    o[0]=f2b(v0[0]); o[1]=f2b(v0[1]); o[2]=f2b(v0[2]); o[3]=f2b(v0[3]);
    o[4]=f2b(v1[0]); o[5]=f2b(v1[1]); o[6]=f2b(v1[2]); o[7]=f2b(v1[3]);
    *(ushort8v*)(xb + (size_t)idx * 8) = o;
  }
}

// ---------- pre_x GEMM ([32768,1024] x [4096,1024]^T) ----------
template<bool FASTA>
__global__ void __launch_bounds__(256)
k_gemm(const ushort* __restrict__ xb, const float* __restrict__ xf,
       const ushort* __restrict__ Wih, ushort* __restrict__ pre) {
  __shared__ ushort As[2][8192];
  __shared__ ushort Bs[2][8192];
  const int tid = threadIdx.x;
  const int lane = tid & 63;
  const int w = tid >> 6;
  const int wm = w & 1, wn = w >> 1;
  const int l15 = lane & 15, kg = lane >> 4;
  const int work = (blockIdx.x & 7) * 1024 + (blockIdx.x >> 3);
  const int rp = work >> 5, cp = work & 31;
  const int m0 = rp * 128, n0 = cp * 128;

  f32x4 acc[4][4];
#pragma unroll
  for (int i = 0; i < 4; ++i)
#pragma unroll
    for (int j = 0; j < 4; ++j) acc[i][j] = f32x4{0.f, 0.f, 0.f, 0.f};

  bf16x8 ra[4], rb[4];

#define LOADTILE(KT)                                                          \
  {                                                                           \
    _Pragma("unroll")                                                         \
    for (int it = 0; it < 4; ++it) {                                          \
      const int idx = it * 256 + tid;                                         \
      const int row = idx >> 3, seg = idx & 7;                                \
      if (FASTA) {                                                            \
        ra[it] = *(const bf16x8*)(xb + (size_t)(m0 + row) * 1024 + (KT) * 64 + seg * 8); \
      } else {                                                                \
        const float* s = xf + (size_t)(m0 + row) * 1024 + (KT) * 64 + seg * 8;\
        f32x4 v0 = *(const f32x4*)s, v1 = *(const f32x4*)(s + 4);             \
        bf16x8 o;                                                             \
        o[0]=(short)f2b(v0[0]); o[1]=(short)f2b(v0[1]);                       \
        o[2]=(short)f2b(v0[2]); o[3]=(short)f2b(v0[3]);                       \
        o[4]=(short)f2b(v1[0]); o[5]=(short)f2b(v1[1]);                       \
        o[6]=(short)f2b(v1[2]); o[7]=(short)f2b(v1[3]);                       \
        ra[it] = o;                                                           \
      }                                                                       \
      rb[it] = *(const bf16x8*)(Wih + (size_t)(n0 + row) * 1024 + (KT) * 64 + seg * 8); \
    }                                                                         \
  }

#define WRITETILE(BUF)                                                        \
  {                                                                           \
    _Pragma("unroll")                                                         \
    for (int it = 0; it < 4; ++it) {                                          \
      const int idx = it * 256 + tid;                                         \
      const int row = idx >> 3, seg = idx & 7;                                \
      const int off = row * 64 + ((seg ^ (row & 7)) << 3);                    \
      *(bf16x8*)(&As[BUF][off]) = ra[it];                                     \
      *(bf16x8*)(&Bs[BUF][off]) = rb[it];                                     \
    }                                                                         \
  }

  LOADTILE(0);
  WRITETILE(0);
  __syncthreads();

#pragma unroll 1
  for (int kt = 0; kt < 16; ++kt) {
    const int cur = kt & 1;
    if (kt < 15) LOADTILE(kt + 1);
#pragma unroll
    for (int ks = 0; ks < 2; ++ks) {
      bf16x8 af[4], bf_[4];
      const int koff = ks * 32 + kg * 8;
      const int swz = koff ^ ((l15 & 7) << 3);
#pragma unroll
      for (int i = 0; i < 4; ++i) {
        const int arow = wm * 64 + i * 16 + l15;
        af[i] = *(const bf16x8*)(&As[cur][arow * 64 + swz]);
        const int brow = wn * 64 + i * 16 + l15;
        bf_[i] = *(const bf16x8*)(&Bs[cur][brow * 64 + swz]);
      }
#pragma unroll
      for (int i = 0; i < 4; ++i)
#pragma unroll
        for (int j = 0; j < 4; ++j)
          acc[i][j] = __builtin_amdgcn_mfma_f32_16x16x32_bf16(af[i], bf_[j], acc[i][j], 0, 0, 0);
    }
    if (kt < 15) WRITETILE(cur ^ 1);
    __syncthreads();
  }

#pragma unroll
  for (int i = 0; i < 4; ++i)
#pragma unroll
    for (int j = 0; j < 4; ++j)
#pragma unroll
      for (int e = 0; e < 4; ++e) {
        const int m = m0 + wm * 64 + i * 16 + kg * 4 + e;
        const int n = n0 + wn * 64 + j * 16 + l15;
        pre[((size_t)(m & 511) * 64 + (m >> 9)) * 4096 + n] = f2b(acc[i][j][e]);
      }
#undef LOADTILE
#undef WRITETILE
}

// ---------- persistent recurrence: per-wave self-release + r12 flag placement ----------
// Protocol: 128-slot ring (fresh-miss plain payload loads, L2-shared) + per-
// producer flags. Wave w consumes only producers j in [16w,16w+16): it polls
// its own 16 flags (one 64B line) and self-releases — no gate barrier, tail =
// max-of-16. Barriers: red-write -> E -> reduce/gates -> E2 -> stores+flag.
// E2's drain is trivial (no pending stores); E's drain of the PREVIOUS step's
// stores overlaps poll+loads+MFMA. Flag issues immediately after the exchange
// store (r12 placement, pre-drain); tags + selective sc1 retry backstop.
__global__ void __launch_bounds__(256, 1)
k_recur(const ushort* __restrict__ Whh_b, const float* __restrict__ bias,
        uint32_t* __restrict__ hrot, const ushort* __restrict__ pre,
        const float* __restrict__ cx,
        const float* __restrict__ wci, const float* __restrict__ wcf,
        const float* __restrict__ wco, float* __restrict__ out,
        uint32_t* __restrict__ fl) {
  __shared__ float red[4][4][16][17];
  const int tid = threadIdx.x;
  const int lane = tid & 63;
  const int w = tid >> 6;
  const int l15 = lane & 15, kg = lane >> 4;
  const int g = blockIdx.x & 3, j = blockIdx.x >> 2;

  // W frags (B-operand): col = gate*1024 + j*16 + l15, k = w*256 + ks*32 + kg*8
  bf16x8 wf[4][8];
#pragma unroll
  for (int gate = 0; gate < 4; ++gate)
#pragma unroll
    for (int ks = 0; ks < 8; ++ks)
      wf[gate][ks] = *(const bf16x8*)(Whh_b
          + (size_t)(gate * 1024 + j * 16 + l15) * 1024 + (w * 8 + ks) * 32 + kg * 8);

  const int grow = tid >> 4, ghl = tid & 15;
  const int brow = g * 16 + grow;
  const int hidx = j * 16 + ghl;
  const float bi = bias[hidx], bff = bias[1024 + hidx],
              bg = bias[2048 + hidx], bo = bias[3072 + hidx];
  const float pci = wci[hidx], pcf = wcf[hidx], pco = wco[hidx];
  float creg = cx[brow * 1024 + hidx];

  const size_t gbase = (size_t)g * CSLOT * 16384;
  const uint32_t* flg = fl + (size_t)g * 512 * 64;     // this group's flag rows
  const int rowoff = l15 * 1024 + w * 256 + kg * 8;    // lane's row + k-slice
  const int srcj = w * 16 + l15;   // wave w's 16 source producers (dup per kg)

  // preload pre[0]
  const ushort* pp0 = pre + ((size_t)brow) * 4096 + hidx;
  float pxi = b2f(pp0[0]), pxf = b2f(pp0[1024]),
        pxg = b2f(pp0[2048]), pxo = b2f(pp0[3072]);

#pragma unroll 1
  for (int t = 0; t < 512; ++t) {
    // [A] per-wave self-release: poll only THIS wave's 16 source flags
    if (t > 0) {
      const uint32_t* fp_ = flg + (size_t)t * 64 + srcj;
      uint32_t v = __hip_atomic_load(fp_, __ATOMIC_RELAXED, __HIP_MEMORY_SCOPE_AGENT);
      while (!__all(v == (uint32_t)t)) {
        __builtin_amdgcn_s_sleep(1);
        v = __hip_atomic_load(fp_, __ATOMIC_RELAXED, __HIP_MEMORY_SCOPE_AGENT);
      }
    }

    // [B] payload loads (plain: fresh MALL fill, L2-shared) + tag backstop
    const uint32_t* hp = hrot + gbase + (size_t)(t & (CSLOT - 1)) * 16384 + rowoff;
    const uint32_t tg = (uint32_t)t << 16;
    uint32_t q[64];
#pragma unroll
    for (int ks = 0; ks < 8; ++ks) {
      u32x4 a = *(const u32x4*)(hp + ks * 32);
      u32x4 b = *(const u32x4*)(hp + ks * 32 + 4);
      q[ks*8+0]=a[0]; q[ks*8+1]=a[1]; q[ks*8+2]=a[2]; q[ks*8+3]=a[3];
      q[ks*8+4]=b[0]; q[ks*8+5]=b[1]; q[ks*8+6]=b[2]; q[ks*8+7]=b[3];
    }
    uint32_t bad = 0;
#pragma unroll
    for (int i = 0; i < 64; ++i) bad |= (q[i] ^ tg);
    while (bad >> 16) {
      // selective sc1 retry of ONLY straggler words (flag/payload race backstop)
#pragma unroll
      for (int i = 0; i < 64; ++i)
        if ((q[i] ^ tg) >> 16)
          q[i] = __hip_atomic_load(hp + (i >> 3) * 32 + (i & 7),
                                   __ATOMIC_RELAXED, __HIP_MEMORY_SCOPE_AGENT);
      bad = 0;
#pragma unroll
      for (int i = 0; i < 64; ++i) bad |= (q[i] ^ tg);
      if (bad >> 16) __builtin_amdgcn_s_sleep(1);
    }
    bf16x8 af[8];
#pragma unroll
    for (int ks = 0; ks < 8; ++ks) {
      bf16x8 a;
      a[0]=(short)(q[ks*8+0]&0xFFFF); a[1]=(short)(q[ks*8+1]&0xFFFF);
      a[2]=(short)(q[ks*8+2]&0xFFFF); a[3]=(short)(q[ks*8+3]&0xFFFF);
      a[4]=(short)(q[ks*8+4]&0xFFFF); a[5]=(short)(q[ks*8+5]&0xFFFF);
      a[6]=(short)(q[ks*8+6]&0xFFFF); a[7]=(short)(q[ks*8+7]&0xFFFF);
      af[ks] = a;
    }

    // [C] prefetch pre[t+1] (register-held; independent of exchange)
    const int tn = (t < 511) ? (t + 1) : 511;
    const ushort* pp = pre + ((size_t)tn * 64 + brow) * 4096 + hidx;
    const ushort nn0 = pp[0], nn1 = pp[1024], nn2 = pp[2048], nn3 = pp[3072];

    // [D] MFMA
    f32x4 acc[4];
#pragma unroll
    for (int gate = 0; gate < 4; ++gate) acc[gate] = f32x4{0.f, 0.f, 0.f, 0.f};
#pragma unroll
    for (int ks = 0; ks < 8; ++ks)
#pragma unroll
      for (int gate = 0; gate < 4; ++gate)
        acc[gate] = __builtin_amdgcn_mfma_f32_16x16x32_bf16(af[ks], wf[gate][ks], acc[gate], 0, 0, 0);

    // K-partials -> LDS (C/D: col=l15, row=kg*4+e)
#pragma unroll
    for (int gate = 0; gate < 4; ++gate)
#pragma unroll
      for (int e = 0; e < 4; ++e)
        red[w][gate][kg * 4 + e][l15] = acc[gate][e];
    __syncthreads();   // [E] red writes -> reads (drains prev step's stores, overlapped)

    // [F] reduce + gates
    float s0 = 0.f, s1 = 0.f, s2 = 0.f, s3 = 0.f;
#pragma unroll
    for (int ww = 0; ww < 4; ++ww) {
      s0 += red[ww][0][grow][ghl];
      s1 += red[ww][1][grow][ghl];
      s2 += red[ww][2][grow][ghl];
      s3 += red[ww][3][grow][ghl];
    }
    const float ig = sigm(s0 + bi + pxi + pci * creg);
    const float fg = sigm(s1 + bff + pxf + pcf * creg);
    const float gg = tanh_f(s2 + bg + pxg);
    const float cy = fg * creg + ig * gg;
    const float og = sigm(s3 + bo + pxo + pco * cy);
    const float hy = og * tanh_f(cy);
    creg = cy;
    __syncthreads();   // [E2] red reads -> next step's writes (trivial drain)

    // [G] stores: exchange payload -> flag (tid0, pre-drain, r12 placement) -> out
    if (t < 511) {
      const uint32_t word = (((uint32_t)(t + 1)) << 16) | (uint32_t)f2b(hy);
      __hip_atomic_store(&hrot[gbase + (size_t)((t + 1) & (CSLOT - 1)) * 16384
                               + (size_t)grow * 1024 + hidx],
                         word, __ATOMIC_RELAXED, __HIP_MEMORY_SCOPE_AGENT);
      if (tid == 0)
        __hip_atomic_store((uint32_t*)(flg + (size_t)(t + 1) * 64 + j),
                           (uint32_t)(t + 1), __ATOMIC_RELAXED,
                           __HIP_MEMORY_SCOPE_AGENT);
    }
    __builtin_nontemporal_store(hy,
        &out[(size_t)brow * 524288 + (size_t)t * 1024 + hidx]);
    pxi = b2f(nn0); pxf = b2f(nn1); pxg = b2f(nn2); pxo = b2f(nn3);
  }
}

// ---------- fallback: per-timestep kernel (known-pass) ----------
template<bool XB>
__global__ void __launch_bounds__(256)
k_step2(const ushort* __restrict__ Whh, const ushort* __restrict__ Wih,
        const float* __restrict__ bias,
        const ushort* __restrict__ hprev, ushort* __restrict__ hnext,
        float* __restrict__ cbuf, const ushort* __restrict__ xb,
        const float* __restrict__ x,
        const float* __restrict__ wci, const float* __restrict__ wcf,
        const float* __restrict__ wco, float* __restrict__ out, int t) {
  __shared__ float pre[32][33];
  const int lane = threadIdx.x & 63;
  const int w = threadIdx.x >> 6;
  const int mt = w & 1, ct = w >> 1;
  const int mg = blockIdx.x & 1, cg = blockIdx.x >> 1;
  const int l15 = lane & 15, kg = lane >> 4;
  const int arow = mg * 32 + mt * 16 + l15;
  const int gate = ct * 2 + (l15 >> 3);
  const int hl = l15 & 7;
  const int gcol = gate * HH + cg * 8 + hl;

  const ushort* wr = Whh + (size_t)gcol * 1024 + kg * 8;
  const ushort* hr = hprev + (size_t)arow * HH + kg * 8;

  f32x4 acc0 = {0.f,0.f,0.f,0.f};
  f32x4 acc1 = {0.f,0.f,0.f,0.f};

#pragma unroll 8
  for (int ks = 0; ks < 32; ks += 2) {
    bf16x8 a0 = *(const bf16x8*)(hr + ks * 32);
    bf16x8 b0 = *(const bf16x8*)(wr + ks * 32);
    acc0 = __builtin_amdgcn_mfma_f32_16x16x32_bf16(a0, b0, acc0, 0, 0, 0);
    bf16x8 a1 = *(const bf16x8*)(hr + ks * 32 + 32);
    bf16x8 b1 = *(const bf16x8*)(wr + ks * 32 + 32);
    acc1 = __builtin_amdgcn_mfma_f32_16x16x32_bf16(a1, b1, acc1, 0, 0, 0);
  }
  const ushort* wrx = Wih + (size_t)gcol * 1024 + kg * 8;
  if (XB) {
    const ushort* xr = xb + ((size_t)t * BB + arow) * II + kg * 8;
#pragma unroll 8
    for (int ks = 0; ks < 32; ks += 2) {
      bf16x8 a0 = *(const bf16x8*)(xr + ks * 32);
      bf16x8 b0 = *(const bf16x8*)(wrx + ks * 32);
      acc0 = __builtin_amdgcn_mfma_f32_16x16x32_bf16(a0, b0, acc0, 0, 0, 0);
      bf16x8 a1 = *(const bf16x8*)(xr + ks * 32 + 32);
      bf16x8 b1 = *(const bf16x8*)(wrx + ks * 32 + 32);
      acc1 = __builtin_amdgcn_mfma_f32_16x16x32_bf16(a1, b1, acc1, 0, 0, 0);
    }
  } else {
    const float* xr = x + ((size_t)arow * TT + t) * II + kg * 8;
#pragma unroll 4
    for (int ks = 0; ks < 32; ++ks) {
      f32x4 v0 = *(const f32x4*)(xr + ks * 32);
      f32x4 v1 = *(const f32x4*)(xr + ks * 32 + 4);
      bf16x8 a;
      a[0]=(short)f2b(v0[0]); a[1]=(short)f2b(v0[1]);
      a[2]=(short)f2b(v0[2]); a[3]=(short)f2b(v0[3]);
      a[4]=(short)f2b(v1[0]); a[5]=(short)f2b(v1[1]);
      a[6]=(short)f2b(v1[2]); a[7]=(short)f2b(v1[3]);
      bf16x8 b0 = *(const bf16x8*)(wrx + ks * 32);
      acc0 = __builtin_amdgcn_mfma_f32_16x16x32_bf16(a, b0, acc0, 0, 0, 0);
    }
  }
  f32x4 acc = acc0 + acc1;

  const float bv = bias[gcol];
  const int lr0 = mt * 16 + kg * 4;
  const int lc2 = ct * 16 + l15;
#pragma unroll
  for (int jj = 0; jj < 4; ++jj) pre[lr0 + jj][lc2] = acc[jj] + bv;
  __syncthreads();

  const int tid = threadIdx.x;
  const int lr = tid >> 3;
  const int hl2 = tid & 7;
  const int b = mg * 32 + lr;
  const int hi = cg * 8 + hl2;
  const float ip = pre[lr][hl2];
  const float fp = pre[lr][8 + hl2];
  const float gp = pre[lr][16 + hl2];
  const float op = pre[lr][24 + hl2];
  const float c = cbuf[b * HH + hi];
  const float ig = sigm(ip + wci[hi] * c);
  const float fg = sigm(fp + wcf[hi] * c);
  const float gg = tanh_f(gp);
  const float cy = fg * c + ig * gg;
  const float og = sigm(op + wco[hi] * cy);
  const float hy = og * tanh_f(cy);
  cbuf[b * HH + hi] = cy;
  hnext[b * HH + hi] = f2b(hy);
  out[((size_t)b * TT + t) * HH + hi] = hy;
}

extern "C" void kernel_launch(void* const* d_in, const int* in_sizes, int n_in,
                              void* d_out, int out_size, void* d_ws, size_t ws_size,
                              hipStream_t stream) {
  const float* x   = (const float*)d_in[0];
  const float* hx  = (const float*)d_in[1];
  const float* cx  = (const float*)d_in[2];
  const float* wih = (const float*)d_in[3];
  const float* whh = (const float*)d_in[4];
  const float* bih = (const float*)d_in[5];
  const float* bhh = (const float*)d_in[6];
  const float* wci = (const float*)d_in[7];
  const float* wcf = (const float*)d_in[8];
  const float* wco = (const float*)d_in[9];
  float* out = (float*)d_out;

  char* ws = (char*)d_ws;
  ushort*   Whh_b = (ushort*)(ws + OFF_WHH);
  ushort*   Wih_b = (ushort*)(ws + OFF_WIH);
  float*    bias  = (float*)(ws + OFF_BIAS);
  uint32_t* fl    = (uint32_t*)(ws + OFF_FL);
  uint32_t* hrot  = (uint32_t*)(ws + OFF_HROT);
  ushort*   hbuf  = (ushort*)(ws + OFF_HBUF);
  float*    cbuf  = (float*)(ws + OFF_CBUF);
  ushort*   pre   = (ushort*)(ws + OFF_PRE);

  k_prep<<<512, 256, 0, stream>>>(wih, whh, bih, bhh, hx, cx,
                                  Whh_b, Wih_b, bias, hbuf, cbuf, hrot, fl);

  if (ws_size >= NEED_A) {
    if (ws_size >= NEED_A2) {
      ushort* xbf = (ushort*)(ws + OFF_XB_A);
      k_convx_flat<<<2048, 256, 0, stream>>>(x, xbf);
      k_gemm<true><<<8192, 256, 0, stream>>>(xbf, x, Wih_b, pre);
    } else {
      k_gemm<false><<<8192, 256, 0, stream>>>(nullptr, x, Wih_b, pre);
    }
    k_recur<<<256, 256, 0, stream>>>(Whh_b, bias, hrot, pre, cx,
                                     wci, wcf, wco, out, fl);
  } else if (ws_size >= NEED_B) {
    ushort* xb = (ushort*)(ws + OFF_XB_B);
    k_convx_tb<<<1024, 256, 0, stream>>>(x, xb);
    for (int t = 0; t < TT; ++t) {
      const ushort* hp = hbuf + (size_t)(t & 1) * BB * HH;
      ushort* hn = hbuf + (size_t)((t + 1) & 1) * BB * HH;
      k_step2<true><<<256, 256, 0, stream>>>(Whh_b, Wih_b, bias, hp, hn, cbuf,
                                             xb, x, wci, wcf, wco, out, t);
    }
  } else {
    for (int t = 0; t < TT; ++t) {
      const ushort* hp = hbuf + (size_t)(t & 1) * BB * HH;
      ushort* hn = hbuf + (size_t)((t + 1) & 1) * BB * HH;
      k_step2<false><<<256, 256, 0, stream>>>(Whh_b, Wih_b, bias, hp, hn, cbuf,
                                              nullptr, x, wci, wcf, wco, out, t);
    }
  }

  // state outputs = INITIAL (hx, cx), per reference
  hipMemcpyAsync(out + 33554432, hx, (size_t)BB * HH * 4,
                 hipMemcpyDeviceToDevice, stream);
  hipMemcpyAsync(out + 33554432 + 65536, cx, (size_t)BB * HH * 4,
                 hipMemcpyDeviceToDevice, stream);
}

// Round 15
// 2445.192 us; speedup vs baseline: 1.3108x; 1.2194x over previous
//
#include <hip/hip_runtime.h>
#include <hip/hip_bf16.h>
#include <cstdint>
#include <cstddef>

#define BB 64
#define TT 512
#define II 1024
#define HH 1024
#define CSLOT 128   // ring slots/group (32MB total >= L2 aggregate: fresh-miss holds)

typedef __attribute__((ext_vector_type(8))) short bf16x8;
typedef __attribute__((ext_vector_type(4))) float f32x4;
typedef __attribute__((ext_vector_type(8))) ushort ushort8v;
typedef __attribute__((ext_vector_type(4))) unsigned int u32x4;

// ---- ws layout (bytes) ----
#define OFF_WHH   0ull            // bf16 [4096][1024]
#define OFF_WIH   8388608ull      // bf16 [4096][1024]
#define OFF_BIAS  16777216ull     // f32 [4096]
#define OFF_FL    16793600ull     // u32 [4][512][64] per-producer flags (512 KB)
#define OFF_HROT  17317888ull     // u32 [4][128][16][1024] tagged exchange (32MB)
#define OFF_HBUF  50872320ull     // bf16 [2][64][1024] (fallback)
#define OFF_CBUF  51134464ull     // f32 [64][1024]     (fallback)
#define OFF_PRE   51396608ull     // bf16 [512][64][4096]
#define OFF_XB_A  319832064ull    // bf16 [32768][1024] (tier A2 only)
#define OFF_XB_B  51396608ull     // bf16 [T][B][I] (fallback tier B)
#define NEED_A2   386940928ull
#define NEED_A    319832064ull
#define NEED_B    118505472ull

__device__ __forceinline__ ushort f2b(float f) {
  union { float f; uint32_t u; } v; v.f = f;
  uint32_t r = v.u + 0x7fffu + ((v.u >> 16) & 1u);
  return (ushort)(r >> 16);
}
__device__ __forceinline__ float b2f(ushort u) {
  union { uint32_t u; float f; } v; v.u = ((uint32_t)u) << 16; return v.f;
}
__device__ __forceinline__ float sigm(float x) { return 1.0f / (1.0f + __expf(-x)); }
__device__ __forceinline__ float tanh_f(float x) {
  float e = __expf(2.0f * x);
  return 1.0f - 2.0f / (e + 1.0f);
}

// ---------- prep ----------
__global__ void k_prep(const float* __restrict__ wih, const float* __restrict__ whh,
                       const float* __restrict__ bih, const float* __restrict__ bhh,
                       const float* __restrict__ hx, const float* __restrict__ cx,
                       ushort* __restrict__ Whh_b, ushort* __restrict__ Wih_b,
                       float* __restrict__ bias, ushort* __restrict__ hbuf0,
                       float* __restrict__ cbuf, uint32_t* __restrict__ hrot,
                       uint32_t* __restrict__ fl) {
  const int tid = blockIdx.x * blockDim.x + threadIdx.x;
  const int nth = gridDim.x * blockDim.x;
  for (int idx = tid; idx < 4096 * 128; idx += nth) {   // chunks of 8
    const size_t o = (size_t)idx * 8;
    f32x4 h0 = *(const f32x4*)(whh + o), h1 = *(const f32x4*)(whh + o + 4);
    f32x4 i0 = *(const f32x4*)(wih + o), i1 = *(const f32x4*)(wih + o + 4);
    ushort8v a, b;
    a[0]=f2b(h0[0]); a[1]=f2b(h0[1]); a[2]=f2b(h0[2]); a[3]=f2b(h0[3]);
    a[4]=f2b(h1[0]); a[5]=f2b(h1[1]); a[6]=f2b(h1[2]); a[7]=f2b(h1[3]);
    b[0]=f2b(i0[0]); b[1]=f2b(i0[1]); b[2]=f2b(i0[2]); b[3]=f2b(i0[3]);
    b[4]=f2b(i1[0]); b[5]=f2b(i1[1]); b[6]=f2b(i1[2]); b[7]=f2b(i1[3]);
    *(ushort8v*)(Whh_b + o) = a;
    *(ushort8v*)(Wih_b + o) = b;
  }
  for (int idx = tid; idx < 4096; idx += nth) bias[idx] = bih[idx] + bhh[idx];
  // clear ALL ring tags except slot 0 (replay safety)
  for (int idx = tid; idx < 4 * CSLOT * 16384; idx += nth) {
    const int slot = (idx >> 14) & (CSLOT - 1);
    if (slot != 0) hrot[idx] = 0xFFFF0000u;
  }
  // clear per-producer flags (one-shot per t; 0xFFFFFFFF != any t)
  for (int idx = tid; idx < 4 * 512 * 64; idx += nth) fl[idx] = 0xFFFFFFFFu;
  for (int idx = tid; idx < BB * HH; idx += nth) {
    const ushort hb = f2b(hx[idx]);
    hbuf0[idx] = hb;
    cbuf[idx] = cx[idx];
    const int brow = idx >> 10, hh = idx & 1023;
    const int g = brow >> 4, r = brow & 15;
    hrot[(size_t)g * CSLOT * 16384 + (size_t)r * 1024 + hh] = (uint32_t)hb;  // tag 0
  }
}

// ---------- x f32 -> bf16, flat [(b*512+t)][I] (tier A2) ----------
__global__ void k_convx_flat(const float* __restrict__ x, ushort* __restrict__ xb) {
  const int tid = blockIdx.x * blockDim.x + threadIdx.x;
  const int nth = gridDim.x * blockDim.x;
  for (size_t idx = tid; idx < 4194304ull; idx += nth) {
    const float* s = x + idx * 8;
    f32x4 v0 = *(const f32x4*)s, v1 = *(const f32x4*)(s + 4);
    ushort8v o;
    o[0]=f2b(v0[0]); o[1]=f2b(v0[1]); o[2]=f2b(v0[2]); o[3]=f2b(v0[3]);
    o[4]=f2b(v1[0]); o[5]=f2b(v1[1]); o[6]=f2b(v1[2]); o[7]=f2b(v1[3]);
    *(ushort8v*)(xb + idx * 8) = o;
  }
}

// ---------- x f32 [B][T][I] -> bf16 [T][B][I] (fallback tier B) ----------
__global__ void k_convx_tb(const float* __restrict__ x, ushort* __restrict__ xb) {
  const int tid = blockIdx.x * blockDim.x + threadIdx.x;
  const int nth = gridDim.x * blockDim.x;
  for (int idx = tid; idx < TT * BB * (II / 8); idx += nth) {
    const int i8 = idx & 127;
    const int tb = idx >> 7;
    const int t = tb >> 6, b = tb & 63;
    const float* src = x + ((size_t)b * TT + t) * II + (size_t)i8 * 8;
    f32x4 v0 = *(const f32x4*)src, v1 = *(const f32x4*)(src + 4);
    ushort8v o;
    o[0]=f2b(v0[0]); o[1]=f2b(v0[1]); o[2]=f2b(v0[2]); o[3]=f2b(v0[3]);
    o[4]=f2b(v1[0]); o[5]=f2b(v1[1]); o[6]=f2b(v1[2]); o[7]=f2b(v1[3]);
    *(ushort8v*)(xb + (size_t)idx * 8) = o;
  }
}

// ---------- pre_x GEMM ([32768,1024] x [4096,1024]^T) ----------
template<bool FASTA>
__global__ void __launch_bounds__(256)
k_gemm(const ushort* __restrict__ xb, const float* __restrict__ xf,
       const ushort* __restrict__ Wih, ushort* __restrict__ pre) {
  __shared__ ushort As[2][8192];
  __shared__ ushort Bs[2][8192];
  const int tid = threadIdx.x;
  const int lane = tid & 63;
  const int w = tid >> 6;
  const int wm = w & 1, wn = w >> 1;
  const int l15 = lane & 15, kg = lane >> 4;
  const int work = (blockIdx.x & 7) * 1024 + (blockIdx.x >> 3);
  const int rp = work >> 5, cp = work & 31;
  const int m0 = rp * 128, n0 = cp * 128;

  f32x4 acc[4][4];
#pragma unroll
  for (int i = 0; i < 4; ++i)
#pragma unroll
    for (int j = 0; j < 4; ++j) acc[i][j] = f32x4{0.f, 0.f, 0.f, 0.f};

  bf16x8 ra[4], rb[4];

#define LOADTILE(KT)                                                          \
  {                                                                           \
    _Pragma("unroll")                                                         \
    for (int it = 0; it < 4; ++it) {                                          \
      const int idx = it * 256 + tid;                                         \
      const int row = idx >> 3, seg = idx & 7;                                \
      if (FASTA) {                                                            \
        ra[it] = *(const bf16x8*)(xb + (size_t)(m0 + row) * 1024 + (KT) * 64 + seg * 8); \
      } else {                                                                \
        const float* s = xf + (size_t)(m0 + row) * 1024 + (KT) * 64 + seg * 8;\
        f32x4 v0 = *(const f32x4*)s, v1 = *(const f32x4*)(s + 4);             \
        bf16x8 o;                                                             \
        o[0]=(short)f2b(v0[0]); o[1]=(short)f2b(v0[1]);                       \
        o[2]=(short)f2b(v0[2]); o[3]=(short)f2b(v0[3]);                       \
        o[4]=(short)f2b(v1[0]); o[5]=(short)f2b(v1[1]);                       \
        o[6]=(short)f2b(v1[2]); o[7]=(short)f2b(v1[3]);                       \
        ra[it] = o;                                                           \
      }                                                                       \
      rb[it] = *(const bf16x8*)(Wih + (size_t)(n0 + row) * 1024 + (KT) * 64 + seg * 8); \
    }                                                                         \
  }

#define WRITETILE(BUF)                                                        \
  {                                                                           \
    _Pragma("unroll")                                                         \
    for (int it = 0; it < 4; ++it) {                                          \
      const int idx = it * 256 + tid;                                         \
      const int row = idx >> 3, seg = idx & 7;                                \
      const int off = row * 64 + ((seg ^ (row & 7)) << 3);                    \
      *(bf16x8*)(&As[BUF][off]) = ra[it];                                     \
      *(bf16x8*)(&Bs[BUF][off]) = rb[it];                                     \
    }                                                                         \
  }

  LOADTILE(0);
  WRITETILE(0);
  __syncthreads();

#pragma unroll 1
  for (int kt = 0; kt < 16; ++kt) {
    const int cur = kt & 1;
    if (kt < 15) LOADTILE(kt + 1);
#pragma unroll
    for (int ks = 0; ks < 2; ++ks) {
      bf16x8 af[4], bf_[4];
      const int koff = ks * 32 + kg * 8;
      const int swz = koff ^ ((l15 & 7) << 3);
#pragma unroll
      for (int i = 0; i < 4; ++i) {
        const int arow = wm * 64 + i * 16 + l15;
        af[i] = *(const bf16x8*)(&As[cur][arow * 64 + swz]);
        const int brow = wn * 64 + i * 16 + l15;
        bf_[i] = *(const bf16x8*)(&Bs[cur][brow * 64 + swz]);
      }
#pragma unroll
      for (int i = 0; i < 4; ++i)
#pragma unroll
        for (int j = 0; j < 4; ++j)
          acc[i][j] = __builtin_amdgcn_mfma_f32_16x16x32_bf16(af[i], bf_[j], acc[i][j], 0, 0, 0);
    }
    if (kt < 15) WRITETILE(cur ^ 1);
    __syncthreads();
  }

#pragma unroll
  for (int i = 0; i < 4; ++i)
#pragma unroll
    for (int j = 0; j < 4; ++j)
#pragma unroll
      for (int e = 0; e < 4; ++e) {
        const int m = m0 + wm * 64 + i * 16 + kg * 4 + e;
        const int n = n0 + wn * 64 + j * 16 + l15;
        pre[((size_t)(m & 511) * 64 + (m >> 9)) * 4096 + n] = f2b(acc[i][j][e]);
      }
#undef LOADTILE
#undef WRITETILE
}

// ---------- persistent recurrence: r12 protocol (measured-best) ----------
// 128-slot ring (fresh-miss plain payload loads, L2-shared) + per-producer
// flags: producer (g,j) stores fl[g][t+1][j]=t+1 (plain sc1, no RMW) right
// after its exchange store; consumer wave 0 polls all 64 flags with ONE
// vector sc1 load, gate __syncthreads releases waves 1-3. Tags + selective
// sc1 retry backstop (correct under any mapping/timing). 2 barriers/step.
__global__ void __launch_bounds__(256, 1)
k_recur(const ushort* __restrict__ Whh_b, const float* __restrict__ bias,
        uint32_t* __restrict__ hrot, const ushort* __restrict__ pre,
        const float* __restrict__ cx,
        const float* __restrict__ wci, const float* __restrict__ wcf,
        const float* __restrict__ wco, float* __restrict__ out,
        uint32_t* __restrict__ fl) {
  __shared__ float red[4][4][16][17];
  const int tid = threadIdx.x;
  const int lane = tid & 63;
  const int w = tid >> 6;
  const int l15 = lane & 15, kg = lane >> 4;
  const int g = blockIdx.x & 3, j = blockIdx.x >> 2;

  // W frags (B-operand): col = gate*1024 + j*16 + l15, k = w*256 + ks*32 + kg*8
  bf16x8 wf[4][8];
#pragma unroll
  for (int gate = 0; gate < 4; ++gate)
#pragma unroll
    for (int ks = 0; ks < 8; ++ks)
      wf[gate][ks] = *(const bf16x8*)(Whh_b
          + (size_t)(gate * 1024 + j * 16 + l15) * 1024 + (w * 8 + ks) * 32 + kg * 8);

  const int grow = tid >> 4, ghl = tid & 15;
  const int brow = g * 16 + grow;
  const int hidx = j * 16 + ghl;
  const float bi = bias[hidx], bff = bias[1024 + hidx],
              bg = bias[2048 + hidx], bo = bias[3072 + hidx];
  const float pci = wci[hidx], pcf = wcf[hidx], pco = wco[hidx];
  float creg = cx[brow * 1024 + hidx];

  const size_t gbase = (size_t)g * CSLOT * 16384;
  const uint32_t* flg = fl + (size_t)g * 512 * 64;     // this group's flag rows
  const int rowoff = l15 * 1024 + w * 256 + kg * 8;    // lane's row + k-slice

  // preload pre[0]
  const ushort* pp0 = pre + ((size_t)brow) * 4096 + hidx;
  float pxi = b2f(pp0[0]), pxf = b2f(pp0[1024]),
        pxg = b2f(pp0[2048]), pxo = b2f(pp0[3072]);

#pragma unroll 1
  for (int t = 0; t < 512; ++t) {
    // flag gate: wave 0 polls all 64 producer flags with one vector sc1 load
    if (t > 0) {
      if (w == 0) {
        const uint32_t* fp_ = flg + (size_t)t * 64 + lane;
        uint32_t v = __hip_atomic_load(fp_, __ATOMIC_RELAXED, __HIP_MEMORY_SCOPE_AGENT);
        while (!__all(v == (uint32_t)t)) {
          __builtin_amdgcn_s_sleep(2);
          v = __hip_atomic_load(fp_, __ATOMIC_RELAXED, __HIP_MEMORY_SCOPE_AGENT);
        }
      }
      __syncthreads();   // releases waves 1-3; also protects red[] reuse
    }

    const uint32_t* hp = hrot + gbase + (size_t)(t & (CSLOT - 1)) * 16384 + rowoff;
    const uint32_t tg = (uint32_t)t << 16;
    uint32_t q[64];
#pragma unroll
    for (int ks = 0; ks < 8; ++ks) {    // PLAIN loads: fresh MALL fill, L2-shared
      u32x4 a = *(const u32x4*)(hp + ks * 32);
      u32x4 b = *(const u32x4*)(hp + ks * 32 + 4);
      q[ks*8+0]=a[0]; q[ks*8+1]=a[1]; q[ks*8+2]=a[2]; q[ks*8+3]=a[3];
      q[ks*8+4]=b[0]; q[ks*8+5]=b[1]; q[ks*8+6]=b[2]; q[ks*8+7]=b[3];
    }
    uint32_t bad = 0;
#pragma unroll
    for (int i = 0; i < 64; ++i) bad |= (q[i] ^ tg);
    while (bad >> 16) {
      // selective sc1 retry of ONLY straggler words (flag/payload race backstop)
#pragma unroll
      for (int i = 0; i < 64; ++i)
        if ((q[i] ^ tg) >> 16)
          q[i] = __hip_atomic_load(hp + (i >> 3) * 32 + (i & 7),
                                   __ATOMIC_RELAXED, __HIP_MEMORY_SCOPE_AGENT);
      bad = 0;
#pragma unroll
      for (int i = 0; i < 64; ++i) bad |= (q[i] ^ tg);
      if (bad >> 16) __builtin_amdgcn_s_sleep(1);
    }
    bf16x8 af[8];
#pragma unroll
    for (int ks = 0; ks < 8; ++ks) {
      bf16x8 a;
      a[0]=(short)(q[ks*8+0]&0xFFFF); a[1]=(short)(q[ks*8+1]&0xFFFF);
      a[2]=(short)(q[ks*8+2]&0xFFFF); a[3]=(short)(q[ks*8+3]&0xFFFF);
      a[4]=(short)(q[ks*8+4]&0xFFFF); a[5]=(short)(q[ks*8+5]&0xFFFF);
      a[6]=(short)(q[ks*8+6]&0xFFFF); a[7]=(short)(q[ks*8+7]&0xFFFF);
      af[ks] = a;
    }

    // prefetch pre[t+1] (register-held; independent of exchange)
    const int tn = (t < 511) ? (t + 1) : 511;
    const ushort* pp = pre + ((size_t)tn * 64 + brow) * 4096 + hidx;
    const ushort nn0 = pp[0], nn1 = pp[1024], nn2 = pp[2048], nn3 = pp[3072];

    f32x4 acc[4];
#pragma unroll
    for (int gate = 0; gate < 4; ++gate) acc[gate] = f32x4{0.f, 0.f, 0.f, 0.f};
#pragma unroll
    for (int ks = 0; ks < 8; ++ks)
#pragma unroll
      for (int gate = 0; gate < 4; ++gate)
        acc[gate] = __builtin_amdgcn_mfma_f32_16x16x32_bf16(af[ks], wf[gate][ks], acc[gate], 0, 0, 0);

    // K-partials -> LDS (C/D: col=l15, row=kg*4+e)
#pragma unroll
    for (int gate = 0; gate < 4; ++gate)
#pragma unroll
      for (int e = 0; e < 4; ++e)
        red[w][gate][kg * 4 + e][l15] = acc[gate][e];
    __syncthreads();

    float s0 = 0.f, s1 = 0.f, s2 = 0.f, s3 = 0.f;
#pragma unroll
    for (int ww = 0; ww < 4; ++ww) {
      s0 += red[ww][0][grow][ghl];
      s1 += red[ww][1][grow][ghl];
      s2 += red[ww][2][grow][ghl];
      s3 += red[ww][3][grow][ghl];
    }
    const float ig = sigm(s0 + bi + pxi + pci * creg);
    const float fg = sigm(s1 + bff + pxf + pcf * creg);
    const float gg = tanh_f(s2 + bg + pxg);
    const float cy = fg * creg + ig * gg;
    const float og = sigm(s3 + bo + pxo + pco * cy);
    const float hy = og * tanh_f(cy);
    creg = cy;
    if (t < 511) {
      const uint32_t word = (((uint32_t)(t + 1)) << 16) | (uint32_t)f2b(hy);
      __hip_atomic_store(&hrot[gbase + (size_t)((t + 1) & (CSLOT - 1)) * 16384
                               + (size_t)grow * 1024 + hidx],
                         word, __ATOMIC_RELAXED, __HIP_MEMORY_SCOPE_AGENT);
      // per-producer flag: one plain sc1 store, no RMW (tags backstop ordering)
      if (tid == 0)
        __hip_atomic_store((uint32_t*)(flg + (size_t)(t + 1) * 64 + j),
                           (uint32_t)(t + 1), __ATOMIC_RELAXED,
                           __HIP_MEMORY_SCOPE_AGENT);
    }
    __builtin_nontemporal_store(hy,
        &out[(size_t)brow * 524288 + (size_t)t * 1024 + hidx]);
    pxi = b2f(nn0); pxf = b2f(nn1); pxg = b2f(nn2); pxo = b2f(nn3);
    // next iteration's post-flag __syncthreads protects red[] reads
  }
}

// ---------- fallback: per-timestep kernel (known-pass) ----------
template<bool XB>
__global__ void __launch_bounds__(256)
k_step2(const ushort* __restrict__ Whh, const ushort* __restrict__ Wih,
        const float* __restrict__ bias,
        const ushort* __restrict__ hprev, ushort* __restrict__ hnext,
        float* __restrict__ cbuf, const ushort* __restrict__ xb,
        const float* __restrict__ x,
        const float* __restrict__ wci, const float* __restrict__ wcf,
        const float* __restrict__ wco, float* __restrict__ out, int t) {
  __shared__ float pre[32][33];
  const int lane = threadIdx.x & 63;
  const int w = threadIdx.x >> 6;
  const int mt = w & 1, ct = w >> 1;
  const int mg = blockIdx.x & 1, cg = blockIdx.x >> 1;
  const int l15 = lane & 15, kg = lane >> 4;
  const int arow = mg * 32 + mt * 16 + l15;
  const int gate = ct * 2 + (l15 >> 3);
  const int hl = l15 & 7;
  const int gcol = gate * HH + cg * 8 + hl;

  const ushort* wr = Whh + (size_t)gcol * 1024 + kg * 8;
  const ushort* hr = hprev + (size_t)arow * HH + kg * 8;

  f32x4 acc0 = {0.f,0.f,0.f,0.f};
  f32x4 acc1 = {0.f,0.f,0.f,0.f};

#pragma unroll 8
  for (int ks = 0; ks < 32; ks += 2) {
    bf16x8 a0 = *(const bf16x8*)(hr + ks * 32);
    bf16x8 b0 = *(const bf16x8*)(wr + ks * 32);
    acc0 = __builtin_amdgcn_mfma_f32_16x16x32_bf16(a0, b0, acc0, 0, 0, 0);
    bf16x8 a1 = *(const bf16x8*)(hr + ks * 32 + 32);
    bf16x8 b1 = *(const bf16x8*)(wr + ks * 32 + 32);
    acc1 = __builtin_amdgcn_mfma_f32_16x16x32_bf16(a1, b1, acc1, 0, 0, 0);
  }
  const ushort* wrx = Wih + (size_t)gcol * 1024 + kg * 8;
  if (XB) {
    const ushort* xr = xb + ((size_t)t * BB + arow) * II + kg * 8;
#pragma unroll 8
    for (int ks = 0; ks < 32; ks += 2) {
      bf16x8 a0 = *(const bf16x8*)(xr + ks * 32);
      bf16x8 b0 = *(const bf16x8*)(wrx + ks * 32);
      acc0 = __builtin_amdgcn_mfma_f32_16x16x32_bf16(a0, b0, acc0, 0, 0, 0);
      bf16x8 a1 = *(const bf16x8*)(xr + ks * 32 + 32);
      bf16x8 b1 = *(const bf16x8*)(wrx + ks * 32 + 32);
      acc1 = __builtin_amdgcn_mfma_f32_16x16x32_bf16(a1, b1, acc1, 0, 0, 0);
    }
  } else {
    const float* xr = x + ((size_t)arow * TT + t) * II + kg * 8;
#pragma unroll 4
    for (int ks = 0; ks < 32; ++ks) {
      f32x4 v0 = *(const f32x4*)(xr + ks * 32);
      f32x4 v1 = *(const f32x4*)(xr + ks * 32 + 4);
      bf16x8 a;
      a[0]=(short)f2b(v0[0]); a[1]=(short)f2b(v0[1]);
      a[2]=(short)f2b(v0[2]); a[3]=(short)f2b(v0[3]);
      a[4]=(short)f2b(v1[0]); a[5]=(short)f2b(v1[1]);
      a[6]=(short)f2b(v1[2]); a[7]=(short)f2b(v1[3]);
      bf16x8 b0 = *(const bf16x8*)(wrx + ks * 32);
      acc0 = __builtin_amdgcn_mfma_f32_16x16x32_bf16(a, b0, acc0, 0, 0, 0);
    }
  }
  f32x4 acc = acc0 + acc1;

  const float bv = bias[gcol];
  const int lr0 = mt * 16 + kg * 4;
  const int lc2 = ct * 16 + l15;
#pragma unroll
  for (int jj = 0; jj < 4; ++jj) pre[lr0 + jj][lc2] = acc[jj] + bv;
  __syncthreads();

  const int tid = threadIdx.x;
  const int lr = tid >> 3;
  const int hl2 = tid & 7;
  const int b = mg * 32 + lr;
  const int hi = cg * 8 + hl2;
  const float ip = pre[lr][hl2];
  const float fp = pre[lr][8 + hl2];
  const float gp = pre[lr][16 + hl2];
  const float op = pre[lr][24 + hl2];
  const float c = cbuf[b * HH + hi];
  const float ig = sigm(ip + wci[hi] * c);
  const float fg = sigm(fp + wcf[hi] * c);
  const float gg = tanh_f(gp);
  const float cy = fg * c + ig * gg;
  const float og = sigm(op + wco[hi] * cy);
  const float hy = og * tanh_f(cy);
  cbuf[b * HH + hi] = cy;
  hnext[b * HH + hi] = f2b(hy);
  out[((size_t)b * TT + t) * HH + hi] = hy;
}

extern "C" void kernel_launch(void* const* d_in, const int* in_sizes, int n_in,
                              void* d_out, int out_size, void* d_ws, size_t ws_size,
                              hipStream_t stream) {
  const float* x   = (const float*)d_in[0];
  const float* hx  = (const float*)d_in[1];
  const float* cx  = (const float*)d_in[2];
  const float* wih = (const float*)d_in[3];
  const float* whh = (const float*)d_in[4];
  const float* bih = (const float*)d_in[5];
  const float* bhh = (const float*)d_in[6];
  const float* wci = (const float*)d_in[7];
  const float* wcf = (const float*)d_in[8];
  const float* wco = (const float*)d_in[9];
  float* out = (float*)d_out;

  char* ws = (char*)d_ws;
  ushort*   Whh_b = (ushort*)(ws + OFF_WHH);
  ushort*   Wih_b = (ushort*)(ws + OFF_WIH);
  float*    bias  = (float*)(ws + OFF_BIAS);
  uint32_t* fl    = (uint32_t*)(ws + OFF_FL);
  uint32_t* hrot  = (uint32_t*)(ws + OFF_HROT);
  ushort*   hbuf  = (ushort*)(ws + OFF_HBUF);
  float*    cbuf  = (float*)(ws + OFF_CBUF);
  ushort*   pre   = (ushort*)(ws + OFF_PRE);

  k_prep<<<512, 256, 0, stream>>>(wih, whh, bih, bhh, hx, cx,
                                  Whh_b, Wih_b, bias, hbuf, cbuf, hrot, fl);

  if (ws_size >= NEED_A) {
    if (ws_size >= NEED_A2) {
      ushort* xbf = (ushort*)(ws + OFF_XB_A);
      k_convx_flat<<<2048, 256, 0, stream>>>(x, xbf);
      k_gemm<true><<<8192, 256, 0, stream>>>(xbf, x, Wih_b, pre);
    } else {
      k_gemm<false><<<8192, 256, 0, stream>>>(nullptr, x, Wih_b, pre);
    }
    k_recur<<<256, 256, 0, stream>>>(Whh_b, bias, hrot, pre, cx,
                                     wci, wcf, wco, out, fl);
  } else if (ws_size >= NEED_B) {
    ushort* xb = (ushort*)(ws + OFF_XB_B);
    k_convx_tb<<<1024, 256, 0, stream>>>(x, xb);
    for (int t = 0; t < TT; ++t) {
      const ushort* hp = hbuf + (size_t)(t & 1) * BB * HH;
      ushort* hn = hbuf + (size_t)((t + 1) & 1) * BB * HH;
      k_step2<true><<<256, 256, 0, stream>>>(Whh_b, Wih_b, bias, hp, hn, cbuf,
                                             xb, x, wci, wcf, wco, out, t);
    }
  } else {
    for (int t = 0; t < TT; ++t) {
      const ushort* hp = hbuf + (size_t)(t & 1) * BB * HH;
      ushort* hn = hbuf + (size_t)((t + 1) & 1) * BB * HH;
      k_step2<false><<<256, 256, 0, stream>>>(Whh_b, Wih_b, bias, hp, hn, cbuf,
                                              nullptr, x, wci, wcf, wco, out, t);
    }
  }

  // state outputs = INITIAL (hx, cx), per reference
  hipMemcpyAsync(out + 33554432, hx, (size_t)BB * HH * 4,
                 hipMemcpyDeviceToDevice, stream);
  hipMemcpyAsync(out + 33554432 + 65536, cx, (size_t)BB * HH * 4,
                 hipMemcpyDeviceToDevice, stream);
}